// Round 2
// 895.670 us; speedup vs baseline: 1.0429x; 1.0429x over previous
//
#include <hip/hip_runtime.h>

#define NSEG 2048
#define EPS 1e-6f
#define GRID 512
#define SPB (NSEG / GRID)   // 4 segments per block
#define NWAVE 4             // 256 threads = 4 waves

// clang-native vector types: required by __builtin_nontemporal_store
typedef float f4 __attribute__((ext_vector_type(4)));
typedef float f2 __attribute__((ext_vector_type(2)));

__device__ __forceinline__ float wave_reduce(float x) {
    #pragma unroll
    for (int off = 32; off > 0; off >>= 1) x += __shfl_down(x, off, 64);
    return x;
}

// One workgroup owns SPB consecutive segments. batch is sorted, so each
// segment is a contiguous node range [i0,i1) found by binary search.
// Per segment: sweep1 (stats, reads allocate in L2/L3) -> block reduce ->
// sweep2 (apply; re-read hits L3 because only 512 blocks x ~250KB = 128MB
// is concurrently resident; output stores are non-temporal so they don't
// evict the re-read set).
__global__ __launch_bounds__(256) void fused_kernel(
        const float* __restrict__ s,
        const float* __restrict__ v,
        const int* __restrict__ batch,
        const float* __restrict__ weight,
        const float* __restrict__ bias,
        float* __restrict__ out, int n) {
    const int lane = threadIdx.x & 63;
    const int w    = threadIdx.x >> 6;

    __shared__ int   sstart[SPB + 1];
    __shared__ float red_s[NWAVE], red_q[NWAVE], red_v[NWAVE];
    __shared__ float p_sm, p_iv, p_im;

    const int g0 = blockIdx.x * SPB;

    // Segment boundaries: lower_bound(batch, g0 + t) for t = 0..SPB
    if (threadIdx.x <= SPB) {
        const int target = g0 + threadIdx.x;
        int lo = 0, hi = n;
        while (lo < hi) {
            const int mid = (lo + hi) >> 1;
            if (batch[mid] < target) lo = mid + 1; else hi = mid;
        }
        sstart[threadIdx.x] = lo;
    }

    // weight/bias fragments are loop-invariant: hoist once per thread.
    const f4 w4 = ((const f4*)weight)[lane];
    const f4 b4 = ((const f4*)bias)[lane];

    float* sout = out;
    float* vout = out + (size_t)n * 256;

    __syncthreads();

    for (int sl = 0; sl < SPB; ++sl) {
        const int i0 = sstart[sl];
        const int i1 = sstart[sl + 1];
        if (i0 >= i1) continue;  // uniform across block: barriers stay balanced

        // ---- sweep 1: segment statistics ----
        float ls = 0.0f, lq = 0.0f, lv = 0.0f;
        #pragma unroll 2
        for (int i = i0 + w; i < i1; i += NWAVE) {
            const f4 x = ((const f4*)(s + (size_t)i * 256))[lane];
            ls += x.x + x.y + x.z + x.w;
            lq += x.x * x.x + x.y * x.y + x.z * x.z + x.w * x.w;
            const f4 y = ((const f4*)(v + (size_t)i * 384))[lane];
            lv += y.x * y.x + y.y * y.y + y.z * y.z + y.w * y.w;
            const f2 z = ((const f2*)(v + (size_t)i * 384 + 256))[lane];
            lv += z.x * z.x + z.y * z.y;
        }
        const float rs = wave_reduce(ls);
        const float rq = wave_reduce(lq);
        const float rv = wave_reduce(lv);
        if (lane == 0) { red_s[w] = rs; red_q[w] = rq; red_v[w] = rv; }
        __syncthreads();   // B1: partials visible

        if (threadIdx.x == 0) {
            const float S = red_s[0] + red_s[1] + red_s[2] + red_s[3];
            const float Q = red_q[0] + red_q[1] + red_q[2] + red_q[3];
            const float V = red_v[0] + red_v[1] + red_v[2] + red_v[3];
            const float nn  = (float)(i1 - i0);        // >= 1 here
            const float sm  = S / (256.0f * nn);
            const float var = fmaxf(Q / (256.0f * nn) - sm * sm, EPS);
            const float vm  = fmaxf(V / (128.0f * nn), EPS);
            p_sm = sm;
            p_iv = 1.0f / var;   // reference divides by var, not sqrt(var)
            p_im = 1.0f / vm;
        }
        __syncthreads();   // B2: params ready (also orders red_* reuse)

        const float sm = p_sm, iv = p_iv, im = p_im;

        // ---- sweep 2: apply (reads hit L3; stores non-temporal) ----
        #pragma unroll 2
        for (int i = i0 + w; i < i1; i += NWAVE) {
            const f4 x = ((const f4*)(s + (size_t)i * 256))[lane];
            f4 o;
            o.x = (x.x - sm) * iv * w4.x + b4.x;
            o.y = (x.y - sm) * iv * w4.y + b4.y;
            o.z = (x.z - sm) * iv * w4.z + b4.z;
            o.w = (x.w - sm) * iv * w4.w + b4.w;
            __builtin_nontemporal_store(o, (f4*)(sout + (size_t)i * 256) + lane);

            f4 y = ((const f4*)(v + (size_t)i * 384))[lane];
            y.x *= im; y.y *= im; y.z *= im; y.w *= im;
            __builtin_nontemporal_store(y, (f4*)(vout + (size_t)i * 384) + lane);

            f2 z = ((const f2*)(v + (size_t)i * 384 + 256))[lane];
            z.x *= im; z.y *= im;
            __builtin_nontemporal_store(z, (f2*)(vout + (size_t)i * 384 + 256) + lane);
        }
        // No barrier needed here: next segment's red_* writes are ordered by
        // B2 (writers passed it), and next p_* write is ordered by next B1.
    }
}

extern "C" void kernel_launch(void* const* d_in, const int* in_sizes, int n_in,
                              void* d_out, int out_size, void* d_ws, size_t ws_size,
                              hipStream_t stream) {
    const float* s      = (const float*)d_in[0];
    const float* v      = (const float*)d_in[1];
    const float* weight = (const float*)d_in[2];
    const float* bias   = (const float*)d_in[3];
    const int*   batch  = (const int*)d_in[4];
    float* out = (float*)d_out;

    const int n = in_sizes[0] / 256;  // number of nodes

    fused_kernel<<<GRID, 256, 0, stream>>>(s, v, batch, weight, bias, out, n);
}

// Round 3
// 889.471 us; speedup vs baseline: 1.0502x; 1.0070x over previous
//
#include <hip/hip_runtime.h>

#define NSEG 2048
#define EPS 1e-6f
#define GRID 1024
#define SPB (NSEG / GRID)   // 2 segments per block
#define NWAVE 4             // 256 threads = 4 waves

// clang-native vector types: required by __builtin_nontemporal_store
typedef float f4 __attribute__((ext_vector_type(4)));
typedef float f2 __attribute__((ext_vector_type(2)));

__device__ __forceinline__ float wave_reduce(float x) {
    #pragma unroll
    for (int off = 32; off > 0; off >>= 1) x += __shfl_down(x, off, 64);
    return x;
}

// One workgroup owns SPB consecutive segments (batch sorted => contiguous
// node ranges, found by binary search). Per segment: sweep1 (stats) ->
// block reduce -> sweep2 (apply). Sweep2's re-read is served by Infinity
// Cache: concurrent resident read-set = GRID x ~245KB ~= 251MB <= 256MB L3
// (verified R2 at GRID=512: FETCH_SIZE == one read of s+v exactly).
// Output stores are non-temporal so they don't evict the re-read set.
// Both sweeps are manually 2-deep software-pipelined: iteration i+1's
// loads issue before iteration i's consumption waits on vmcnt, keeping
// >=2x16B loads per lane in flight (latency-bound fix; R2 VALUBusy=5%).
__global__ __launch_bounds__(256) void fused_kernel(
        const float* __restrict__ s,
        const float* __restrict__ v,
        const int* __restrict__ batch,
        const float* __restrict__ weight,
        const float* __restrict__ bias,
        float* __restrict__ out, int n) {
    const int lane = threadIdx.x & 63;
    const int w    = threadIdx.x >> 6;

    __shared__ int   sstart[SPB + 1];
    __shared__ float red_s[NWAVE], red_q[NWAVE], red_v[NWAVE];
    __shared__ float p_sm, p_iv, p_im;

    const int g0 = blockIdx.x * SPB;

    // Segment boundaries: lower_bound(batch, g0 + t) for t = 0..SPB
    if (threadIdx.x <= SPB) {
        const int target = g0 + threadIdx.x;
        int lo = 0, hi = n;
        while (lo < hi) {
            const int mid = (lo + hi) >> 1;
            if (batch[mid] < target) lo = mid + 1; else hi = mid;
        }
        sstart[threadIdx.x] = lo;
    }

    // weight/bias fragments are loop-invariant: hoist once per thread.
    const f4 w4 = ((const f4*)weight)[lane];
    const f4 b4 = ((const f4*)bias)[lane];

    float* sout = out;
    float* vout = out + (size_t)n * 256;

    __syncthreads();

    for (int sl = 0; sl < SPB; ++sl) {
        const int i0 = sstart[sl];
        const int i1 = sstart[sl + 1];
        if (i0 >= i1) continue;  // uniform across block: barriers stay balanced

        // ---- sweep 1: segment statistics (2-deep pipelined) ----
        float ls = 0.0f, lq = 0.0f, lv = 0.0f;
        int i = i0 + w;
        const bool have = (i < i1);
        f4 x0 = {0,0,0,0}, y0 = {0,0,0,0};
        f2 z0 = {0,0};
        if (have) {
            x0 = ((const f4*)(s + (size_t)i * 256))[lane];
            y0 = ((const f4*)(v + (size_t)i * 384))[lane];
            z0 = ((const f2*)(v + (size_t)i * 384 + 256))[lane];
        }
        for (; i + NWAVE < i1; i += NWAVE) {
            const int j = i + NWAVE;
            const f4 x1 = ((const f4*)(s + (size_t)j * 256))[lane];
            const f4 y1 = ((const f4*)(v + (size_t)j * 384))[lane];
            const f2 z1 = ((const f2*)(v + (size_t)j * 384 + 256))[lane];
            ls += x0.x + x0.y + x0.z + x0.w;
            lq += x0.x * x0.x + x0.y * x0.y + x0.z * x0.z + x0.w * x0.w;
            lv += y0.x * y0.x + y0.y * y0.y + y0.z * y0.z + y0.w * y0.w;
            lv += z0.x * z0.x + z0.y * z0.y;
            x0 = x1; y0 = y1; z0 = z1;
        }
        if (have) {
            ls += x0.x + x0.y + x0.z + x0.w;
            lq += x0.x * x0.x + x0.y * x0.y + x0.z * x0.z + x0.w * x0.w;
            lv += y0.x * y0.x + y0.y * y0.y + y0.z * y0.z + y0.w * y0.w;
            lv += z0.x * z0.x + z0.y * z0.y;
        }

        const float rs = wave_reduce(ls);
        const float rq = wave_reduce(lq);
        const float rv = wave_reduce(lv);
        if (lane == 0) { red_s[w] = rs; red_q[w] = rq; red_v[w] = rv; }
        __syncthreads();   // B1: partials visible

        if (threadIdx.x == 0) {
            const float S = red_s[0] + red_s[1] + red_s[2] + red_s[3];
            const float Q = red_q[0] + red_q[1] + red_q[2] + red_q[3];
            const float V = red_v[0] + red_v[1] + red_v[2] + red_v[3];
            const float nn  = (float)(i1 - i0);        // >= 1 here
            const float sm  = S / (256.0f * nn);
            const float var = fmaxf(Q / (256.0f * nn) - sm * sm, EPS);
            const float vm  = fmaxf(V / (128.0f * nn), EPS);
            p_sm = sm;
            p_iv = 1.0f / var;   // reference divides by var, not sqrt(var)
            p_im = 1.0f / vm;
        }
        __syncthreads();   // B2: params ready (also orders red_* reuse)

        const float sm = p_sm, iv = p_iv, im = p_im;

        // ---- sweep 2: apply (L3-hit reads, nt stores; 2-deep pipelined) ----
        i = i0 + w;
        if (have) {
            x0 = ((const f4*)(s + (size_t)i * 256))[lane];
            y0 = ((const f4*)(v + (size_t)i * 384))[lane];
            z0 = ((const f2*)(v + (size_t)i * 384 + 256))[lane];
        }
        for (; i + NWAVE < i1; i += NWAVE) {
            const int j = i + NWAVE;
            const f4 x1 = ((const f4*)(s + (size_t)j * 256))[lane];
            const f4 y1 = ((const f4*)(v + (size_t)j * 384))[lane];
            const f2 z1 = ((const f2*)(v + (size_t)j * 384 + 256))[lane];

            f4 o;
            o.x = (x0.x - sm) * iv * w4.x + b4.x;
            o.y = (x0.y - sm) * iv * w4.y + b4.y;
            o.z = (x0.z - sm) * iv * w4.z + b4.z;
            o.w = (x0.w - sm) * iv * w4.w + b4.w;
            __builtin_nontemporal_store(o, (f4*)(sout + (size_t)i * 256) + lane);
            f4 yo = y0; yo.x *= im; yo.y *= im; yo.z *= im; yo.w *= im;
            __builtin_nontemporal_store(yo, (f4*)(vout + (size_t)i * 384) + lane);
            f2 zo = z0; zo.x *= im; zo.y *= im;
            __builtin_nontemporal_store(zo, (f2*)(vout + (size_t)i * 384 + 256) + lane);

            x0 = x1; y0 = y1; z0 = z1;
        }
        if (have) {
            f4 o;
            o.x = (x0.x - sm) * iv * w4.x + b4.x;
            o.y = (x0.y - sm) * iv * w4.y + b4.y;
            o.z = (x0.z - sm) * iv * w4.z + b4.z;
            o.w = (x0.w - sm) * iv * w4.w + b4.w;
            __builtin_nontemporal_store(o, (f4*)(sout + (size_t)i * 256) + lane);
            f4 yo = y0; yo.x *= im; yo.y *= im; yo.z *= im; yo.w *= im;
            __builtin_nontemporal_store(yo, (f4*)(vout + (size_t)i * 384) + lane);
            f2 zo = z0; zo.x *= im; zo.y *= im;
            __builtin_nontemporal_store(zo, (f2*)(vout + (size_t)i * 384 + 256) + lane);
        }
        // No barrier needed here: next segment's red_* writes are ordered by
        // B2 (writers passed it), and next p_* write is ordered by next B1.
    }
}

extern "C" void kernel_launch(void* const* d_in, const int* in_sizes, int n_in,
                              void* d_out, int out_size, void* d_ws, size_t ws_size,
                              hipStream_t stream) {
    const float* s      = (const float*)d_in[0];
    const float* v      = (const float*)d_in[1];
    const float* weight = (const float*)d_in[2];
    const float* bias   = (const float*)d_in[3];
    const int*   batch  = (const int*)d_in[4];
    float* out = (float*)d_out;

    const int n = in_sizes[0] / 256;  // number of nodes

    fused_kernel<<<GRID, 256, 0, stream>>>(s, v, batch, weight, bias, out, n);
}